// Round 10
// baseline (9909.294 us; speedup 1.0000x reference)
//
#include <hip/hip_runtime.h>
#include <cstdint>
#include <cstddef>

#define TLEN 512
#define BATCH 1000
#define NEVS 102400   // events per source
#define HID 64

__device__ __forceinline__ float fast_rcp(float x) {
#if __has_builtin(__builtin_amdgcn_rcpf)
    return __builtin_amdgcn_rcpf(x);
#else
    return 1.0f / x;
#endif
}
__device__ __forceinline__ float sigm(float x) { return fast_rcp(1.0f + __expf(-x)); }
__device__ __forceinline__ float tanh_f(float x) { return fmaf(2.0f, sigm(2.0f * x), -1.0f); }

// Wave-wide sum broadcast (rocPRIM gfx9 DPP pattern).
__device__ __forceinline__ float wave_sum_bcast(float x) {
#if __has_builtin(__builtin_amdgcn_update_dpp) && __has_builtin(__builtin_amdgcn_readlane)
    x += __int_as_float(__builtin_amdgcn_update_dpp(0, __float_as_int(x), 0x111, 0xf, 0xf, true)); // row_shr:1
    x += __int_as_float(__builtin_amdgcn_update_dpp(0, __float_as_int(x), 0x112, 0xf, 0xf, true)); // row_shr:2
    x += __int_as_float(__builtin_amdgcn_update_dpp(0, __float_as_int(x), 0x114, 0xf, 0xf, true)); // row_shr:4
    x += __int_as_float(__builtin_amdgcn_update_dpp(0, __float_as_int(x), 0x118, 0xf, 0xf, true)); // row_shr:8
    x += __int_as_float(__builtin_amdgcn_update_dpp(0, __float_as_int(x), 0x142, 0xa, 0xf, true)); // row_bcast:15
    x += __int_as_float(__builtin_amdgcn_update_dpp(0, __float_as_int(x), 0x143, 0xc, 0xf, true)); // row_bcast:31
    return __int_as_float(__builtin_amdgcn_readlane(__float_as_int(x), 63));
#else
#pragma unroll
    for (int off = 1; off < 64; off <<= 1) x += __shfl_xor(x, off, 64);
    return x;
#endif
}

// Two independent wave sums, stages interleaved for ILP.
__device__ __forceinline__ void wave_sum2(float& a, float& b) {
#if __has_builtin(__builtin_amdgcn_update_dpp) && __has_builtin(__builtin_amdgcn_readlane)
    int ta, tb;
    ta = __builtin_amdgcn_update_dpp(0, __float_as_int(a), 0x111, 0xf, 0xf, true);
    tb = __builtin_amdgcn_update_dpp(0, __float_as_int(b), 0x111, 0xf, 0xf, true);
    a += __int_as_float(ta); b += __int_as_float(tb);
    ta = __builtin_amdgcn_update_dpp(0, __float_as_int(a), 0x112, 0xf, 0xf, true);
    tb = __builtin_amdgcn_update_dpp(0, __float_as_int(b), 0x112, 0xf, 0xf, true);
    a += __int_as_float(ta); b += __int_as_float(tb);
    ta = __builtin_amdgcn_update_dpp(0, __float_as_int(a), 0x114, 0xf, 0xf, true);
    tb = __builtin_amdgcn_update_dpp(0, __float_as_int(b), 0x114, 0xf, 0xf, true);
    a += __int_as_float(ta); b += __int_as_float(tb);
    ta = __builtin_amdgcn_update_dpp(0, __float_as_int(a), 0x118, 0xf, 0xf, true);
    tb = __builtin_amdgcn_update_dpp(0, __float_as_int(b), 0x118, 0xf, 0xf, true);
    a += __int_as_float(ta); b += __int_as_float(tb);
    ta = __builtin_amdgcn_update_dpp(0, __float_as_int(a), 0x142, 0xa, 0xf, true);
    tb = __builtin_amdgcn_update_dpp(0, __float_as_int(b), 0x142, 0xa, 0xf, true);
    a += __int_as_float(ta); b += __int_as_float(tb);
    ta = __builtin_amdgcn_update_dpp(0, __float_as_int(a), 0x143, 0xc, 0xf, true);
    tb = __builtin_amdgcn_update_dpp(0, __float_as_int(b), 0x143, 0xc, 0xf, true);
    a += __int_as_float(ta); b += __int_as_float(tb);
    a = __int_as_float(__builtin_amdgcn_readlane(__float_as_int(a), 63));
    b = __int_as_float(__builtin_amdgcn_readlane(__float_as_int(b), 63));
#else
    a = wave_sum_bcast(a); b = wave_sum_bcast(b);
#endif
}

// ===========================================================================
// Event binning by ti (r2-proven): count -> scan -> scatter. Makes every
// (src, chunk) a contiguous same-source range of `order`.
// ===========================================================================
__global__ __launch_bounds__(256) void bin_zero_kernel(int* __restrict__ cnt)
{
    int i = blockIdx.x * 256 + threadIdx.x;
    if (i < 5 * 512) cnt[i] = 0;
}

__global__ __launch_bounds__(256) void bin_count_kernel(
    const int* __restrict__ t0, const int* __restrict__ t1,
    const int* __restrict__ t2, const int* __restrict__ t3,
    const int* __restrict__ t4, int* __restrict__ cnt)
{
    const int src = blockIdx.y;
    const int* ti = src == 0 ? t0 : src == 1 ? t1 : src == 2 ? t2 : src == 3 ? t3 : t4;
    const int e = blockIdx.x * 256 + threadIdx.x;
    atomicAdd(&cnt[src * 512 + ti[e]], 1);
}

__global__ __launch_bounds__(512) void bin_scan_kernel(
    const int* __restrict__ cnt, int* __restrict__ startp, int* __restrict__ cur)
{
    const int src = blockIdx.x, tid = threadIdx.x;
    __shared__ int s[512];
    const int v = cnt[src * 512 + tid];
    s[tid] = v;
    __syncthreads();
    for (int off = 1; off < 512; off <<= 1) {
        int t = (tid >= off) ? s[tid - off] : 0;
        __syncthreads();
        s[tid] += t;
        __syncthreads();
    }
    const int inc = s[tid];
    startp[src * 513 + tid] = inc - v;
    cur[src * 512 + tid] = inc - v;
    if (tid == 511) startp[src * 513 + 512] = inc;
}

__global__ __launch_bounds__(256) void bin_scatter_kernel(
    const int* __restrict__ t0, const int* __restrict__ t1,
    const int* __restrict__ t2, const int* __restrict__ t3,
    const int* __restrict__ t4, int* __restrict__ cur, int* __restrict__ order)
{
    const int src = blockIdx.y;
    const int* ti = src == 0 ? t0 : src == 1 ? t1 : src == 2 ? t2 : src == 3 ? t3 : t4;
    const int e = blockIdx.x * 256 + threadIdx.x;
    const int off = atomicAdd(&cur[src * 512 + ti[e]], 1);
    order[(size_t)src * NEVS + off] = e;
}

// ===========================================================================
// Composed projection weights: wp[row][col], row=(src,j) [130], col=dir*256+r.
// ===========================================================================
__global__ __launch_bounds__(512) void compose_kernel(
    const float* __restrict__ W0, const float* __restrict__ B0,
    const float* __restrict__ W1, const float* __restrict__ B1,
    const float* __restrict__ W2, const float* __restrict__ B2,
    const float* __restrict__ W3, const float* __restrict__ B3,
    const float* __restrict__ W4, const float* __restrict__ B4,
    const float* __restrict__ Wih, const float* __restrict__ bih,
    const float* __restrict__ bhh, float* __restrict__ wp)
{
    const int col = threadIdx.x;   // 0..511 == dir*256 + r == Wih row index
    const int row = blockIdx.x;    // 0..129
    const float* srcW; const float* srcB; int base, IND;
    if (row < 9)        { srcW = W0; srcB = B0; base = 0;   IND = 8;  }
    else if (row < 27)  { srcW = W1; srcB = B1; base = 9;   IND = 17; }
    else if (row < 53)  { srcW = W2; srcB = B2; base = 27;  IND = 25; }
    else if (row < 120) { srcW = W3; srcB = B3; base = 53;  IND = 66; }
    else                { srcW = W4; srcB = B4; base = 120; IND = 9;  }
    const int j = row - base;
    const float* xrow = (j < IND) ? (srcW + (size_t)j * 64) : srcB;
    const float* wr = Wih + (size_t)col * 64;
    float acc = 0.0f;
#pragma unroll
    for (int h2 = 0; h2 < 64; ++h2) acc = fmaf(xrow[h2], wr[h2], acc);
    if (j == IND) acc += bih[col] + bhh[col];
    wp[(size_t)row * 512 + col] = acc;
}

__device__ __forceinline__ void fma4(float4& a, float x, const float4 w) {
    a.x = fmaf(x, w.x, a.x); a.y = fmaf(x, w.y, a.y);
    a.z = fmaf(x, w.z, a.z); a.w = fmaf(x, w.w, a.w);
}

// ===========================================================================
// project_tile: per (src, dir), events of this chunk come from the binned
// contiguous range. 64-event same-source tiles: gather -> xT (transposed,
// padded bias/zeros) -> GEMM vs LDS-resident W' -> contiguous 1KB row stores.
// Thread = (wave = 8-event group, lane = 4-col group): per row
// 1 conflict-free w-b128 + 2 broadcast x-b128 + 32 FMA.
// ===========================================================================
template<int PR, int BASE, int SRC>
__device__ __forceinline__ void tile_loop(
    const float* __restrict__ num, const int* __restrict__ cat,
    const float* __restrict__ tab, const int* __restrict__ bi,
    const int* __restrict__ ti,
    const int* __restrict__ order_s, const int* __restrict__ start_s,
    const float* __restrict__ wT, float (*xT)[68], int* pos,
    float* __restrict__ gdst, int dir, int lo, int hi, int tcm)
{
    const int tid = threadIdx.x;
    const int lane = tid & 63, eg = tid >> 6;   // eg = wave = 8-event group

    const int r0 = start_s[lo];
    const int r1 = start_s[hi];
    const int ntiles = (r1 - r0 + 63) >> 6;

    for (int tile = blockIdx.x; tile < ntiles; tile += gridDim.x) {
        const int ta0 = r0 + (tile << 6);
        int ne = r1 - ta0; if (ne > 64) ne = 64;

        // ---- gather: wave i handles events i, i+8, ... (lane = value idx) ----
#pragma unroll
        for (int k = 0; k < 8; ++k) {
            const int i = eg + 8 * k;
            if (i < ne) {
                const int e = order_s[ta0 + i];
                const int v = lane;
                if (v == 0) {
                    const int t = ti[e];
                    const int lt = dir ? (hi - 1 - t) : (t - lo);
                    pos[i] = bi[e] * tcm + lt;
                }
                if (SRC == 0) {
                    if (v < 12) xT[v][i] = (v < 8) ? num[(size_t)e * 8 + v]
                                                   : (v == 8 ? 1.f : 0.f);
                } else if (SRC == 1) {
                    if (v < 20) xT[v][i] = (v < 16)
                        ? tab[(size_t)cat[e * 2 + (v >> 3)] * 8 + (v & 7)]
                        : (v == 16 ? num[e] : (v == 17 ? 1.f : 0.f));
                } else if (SRC == 2) {
                    if (v < 28) xT[v][i] = (v < 24)
                        ? tab[(size_t)cat[e * 3 + (v >> 3)] * 8 + (v & 7)]
                        : (v == 24 ? num[e] : (v == 25 ? 1.f : 0.f));
                } else if (SRC == 3) {
                    xT[v][i] = tab[(size_t)cat[e * 8 + (v >> 3)] * 8 + (v & 7)];
                    if (v < 4) xT[64 + v][i] = (v < 2) ? num[(size_t)e * 2 + v]
                                                       : (v == 2 ? 1.f : 0.f);
                } else {
                    if (v < 12) xT[v][i] = (v < 8) ? tab[(size_t)cat[e] * 8 + v]
                        : (v == 8 ? num[e] : (v == 9 ? 1.f : 0.f));
                }
            }
        }
        __syncthreads();

        // ---- GEMM: 8 events (this wave) x 4 cols (this lane) ----
        float4 acc[8];
#pragma unroll
        for (int k = 0; k < 8; ++k) acc[k] = make_float4(0.f, 0.f, 0.f, 0.f);
#pragma unroll
        for (int r = 0; r < PR; ++r) {
            const float4 w4 = *(const float4*)&wT[(size_t)(BASE + r) * 256 + 4 * lane];
            const float4 xa = *(const float4*)&xT[r][8 * eg];
            const float4 xb = *(const float4*)&xT[r][8 * eg + 4];
            fma4(acc[0], xa.x, w4); fma4(acc[1], xa.y, w4);
            fma4(acc[2], xa.z, w4); fma4(acc[3], xa.w, w4);
            fma4(acc[4], xb.x, w4); fma4(acc[5], xb.y, w4);
            fma4(acc[6], xb.z, w4); fma4(acc[7], xb.w, w4);
        }
#pragma unroll
        for (int k = 0; k < 8; ++k) {
            const int ev = 8 * eg + k;
            if (ev < ne)
                *(float4*)&gdst[(size_t)pos[ev] * 256 + 4 * lane] = acc[k];
        }
        __syncthreads();   // protect xT/pos before next tile
    }
}

__global__ __launch_bounds__(512, 1) void project_tile_kernel(
    const float* __restrict__ ccba_num, const int* __restrict__ ccba_bi, const int* __restrict__ ccba_ti,
    const float* __restrict__ cdtx_num, const int* __restrict__ cdtx_cat, const float* __restrict__ cdtx_tab,
    const int* __restrict__ cdtx_bi, const int* __restrict__ cdtx_ti,
    const float* __restrict__ cust_num, const int* __restrict__ cust_cat, const float* __restrict__ cust_tab,
    const int* __restrict__ cust_bi, const int* __restrict__ cust_ti,
    const float* __restrict__ dp_num, const int* __restrict__ dp_cat, const float* __restrict__ dp_tab,
    const int* __restrict__ dp_bi, const int* __restrict__ dp_ti,
    const float* __restrict__ remit_num, const int* __restrict__ remit_cat, const float* __restrict__ remit_tab,
    const int* __restrict__ remit_bi, const int* __restrict__ remit_ti,
    const float* __restrict__ wp, const int* __restrict__ order, const int* __restrict__ startp,
    float* __restrict__ gf, float* __restrict__ gb,
    int f0, int len, int tcm)
{
    __shared__ float wT[132 * 256];   // 135.2 KB: this dir's half of W', rows 130/131 = 0
    __shared__ float xT[68][68];      // 18.5 KB transposed padded x (stride 68: 16B-aligned)
    __shared__ int pos[64];

    const int tid = threadIdx.x;
    const int dir = blockIdx.y & 1;
    const int src = blockIdx.y >> 1;
    const int lo = dir ? (TLEN - f0 - len) : f0;   // bwd chunk = mirrored range
    const int hi = lo + len;
    float* gdst = dir ? gb : gf;

    // stage W' (this dir's 256-col half; rows 130/131 zero for padding)
    {
        const float4* wp4 = (const float4*)wp;   // 130 rows x 128 float4
        float4* wT4 = (float4*)wT;
        for (int i = tid; i < 132 * 64; i += 512) {
            const int row = i >> 6, c4 = i & 63;
            wT4[i] = (row < 130) ? wp4[(row << 7) + (dir << 6) + c4]
                                 : make_float4(0.f, 0.f, 0.f, 0.f);
        }
    }
    __syncthreads();

    const int* order_s = order + (size_t)src * NEVS;
    const int* start_s = startp + src * 513;
    switch (src) {
    case 0: tile_loop<12, 0, 0>(ccba_num, nullptr, nullptr, ccba_bi, ccba_ti,
                                order_s, start_s, wT, xT, pos, gdst, dir, lo, hi, tcm); break;
    case 1: tile_loop<20, 9, 1>(cdtx_num, cdtx_cat, cdtx_tab, cdtx_bi, cdtx_ti,
                                order_s, start_s, wT, xT, pos, gdst, dir, lo, hi, tcm); break;
    case 2: tile_loop<28, 27, 2>(cust_num, cust_cat, cust_tab, cust_bi, cust_ti,
                                 order_s, start_s, wT, xT, pos, gdst, dir, lo, hi, tcm); break;
    case 3: tile_loop<68, 53, 3>(dp_num, dp_cat, dp_tab, dp_bi, dp_ti,
                                 order_s, start_s, wT, xT, pos, gdst, dir, lo, hi, tcm); break;
    default: tile_loop<12, 120, 4>(remit_num, remit_cat, remit_tab, remit_bi, remit_ti,
                                   order_s, start_s, wT, xT, pos, gdst, dir, lo, hi, tcm); break;
    }
}

// ===========================================================================
// Layer-0 recurrence over the precomputed chunk (r2-proven): one wave per
// (b,dir); 2000 concurrent chains; 2-step gate prefetch; (h,c) carried.
// ===========================================================================
__global__ __launch_bounds__(256) void rec_chunk_kernel(
    const float* __restrict__ gf, const float* __restrict__ gb,
    const float* __restrict__ Whh, const float* __restrict__ Whr,
    float* __restrict__ h0, float* __restrict__ hs, float* __restrict__ cs,
    int f0, int len, int tcm, int first)
{
    const int wv = threadIdx.x >> 6, lane = threadIdx.x & 63;
    const int p = blockIdx.x * 4 + wv;          // 0..1999
    const int b = p >> 1, dir = p & 1;

    float whh4[4];
#pragma unroll
    for (int k = 0; k < 4; ++k) whh4[k] = Whh[dir * 256 + k * 64 + lane];
    const float whr = Whr[dir * HID + lane];

    const float* g = (dir ? gb : gf) + (size_t)b * tcm * 256 + lane;
    float* h0p = h0 + (size_t)b * TLEN * 2 + dir;

    float h, c;
    if (first) { h = 0.0f; c = 0.0f; }
    else       { h = hs[p]; c = cs[(size_t)p * 64 + lane]; }

    auto ga = [&](int s) -> const float* {
        const int sc = (s < len) ? s : (len - 1);   // clamp; value unused past end
        return g + (size_t)sc * 256;
    };
    auto do_step = [&](const float (&G)[4], int s) {
        const float gi = fmaf(whh4[0], h, G[0]);
        const float gfv = fmaf(whh4[1], h, G[1]);
        const float gg = fmaf(whh4[2], h, G[2]);
        const float go = fmaf(whh4[3], h, G[3]);
        c = sigm(gfv) * c + sigm(gi) * tanh_f(gg);
        h = wave_sum_bcast(sigm(go) * tanh_f(c) * whr);
        const int t_out = dir ? (TLEN - 1 - f0 - s) : (f0 + s);
        if (lane == 0) h0p[(size_t)t_out * 2] = h;
    };

    float A[4], B[4];
    {
        const float* pa = ga(0); const float* pb = ga(1);
#pragma unroll
        for (int k = 0; k < 4; ++k) { A[k] = pa[k * 64]; B[k] = pb[k * 64]; }
    }
    for (int s = 0; s < len; s += 2) {
        float C[4], D[4];
        const float* pc = ga(s + 2); const float* pd = ga(s + 3);
#pragma unroll
        for (int k = 0; k < 4; ++k) { C[k] = pc[k * 64]; D[k] = pd[k * 64]; }
        do_step(A, s);
        if (s + 1 < len) do_step(B, s + 1);
#pragma unroll
        for (int k = 0; k < 4; ++k) { A[k] = C[k]; B[k] = D[k]; }
    }
    if (lane == 0) hs[p] = h;
    cs[(size_t)p * 64 + lane] = c;
}

// ===========================================================================
// LSTM layer 1 (insz=2): one wave per b, BOTH dirs interleaved.
// NEW: h0 inputs staged to LDS (16 KB/block) — r2 (1-chain) and r7 (2-chain)
// both measured exactly 178 us -> the serial chain is x-LOAD-latency-bound;
// LDS reads (~60cy) put it back to issue-bound.
// ===========================================================================
__global__ __launch_bounds__(256, 2) void lstm1_kernel(
    const float* __restrict__ h0, const float* __restrict__ Wih,
    const float* __restrict__ Whh, const float* __restrict__ Whr,
    const float* __restrict__ bih, const float* __restrict__ bhh,
    float* __restrict__ h1)
{
    __shared__ float2 xsh[4][TLEN];
    const int w = threadIdx.x >> 6, lane = threadIdx.x & 63;
    const int b0 = blockIdx.x * 4;
    const int b = b0 + w;                      // grid 250 -> b 0..999

    // stage 4 sequences' x (coalesced float2)
    {
        const float2* src = (const float2*)(h0 + (size_t)b0 * TLEN * 2);
        for (int i = threadIdx.x; i < 4 * TLEN; i += 256)
            xsh[i >> 9][i & 511] = src[i];
    }

    const volatile float* vWih = Wih;
    const volatile float* vWhh = Whh;
    const volatile float* vWhr = Whr;
    const volatile float* vbih = bih;
    const volatile float* vbhh = bhh;

    float wi0[2][4], wi1[2][4], whh[2][4], bias[2][4], whr[2];
#pragma unroll
    for (int d = 0; d < 2; ++d) {
#pragma unroll
        for (int k = 0; k < 4; ++k) {
            const int r = d * 256 + k * 64 + lane;
            wi0[d][k] = vWih[(size_t)r * 2 + 0];
            wi1[d][k] = vWih[(size_t)r * 2 + 1];
            whh[d][k] = vWhh[r];
            bias[d][k] = vbih[r] + vbhh[r];
        }
        whr[d] = vWhr[d * HID + lane];
    }
    __syncthreads();

    float hA = 0, cA = 0, hB = 0, cB = 0;
    const float2* hb = xsh[w];

    float2 xA = hb[0];            // fwd t=0
    float2 xB = hb[TLEN - 1];     // bwd t=511
    for (int t = 0; t < TLEN; ++t) {
        const int tn = (t + 1 < TLEN) ? t + 1 : t;
        const float2 xAn = hb[tn];
        const float2 xBn = hb[TLEN - 1 - tn];
        float gA[4], gB[4];
#pragma unroll
        for (int k = 0; k < 4; ++k) {
            gA[k] = fmaf(whh[0][k], hA, fmaf(wi1[0][k], xA.y, fmaf(wi0[0][k], xA.x, bias[0][k])));
            gB[k] = fmaf(whh[1][k], hB, fmaf(wi1[1][k], xB.y, fmaf(wi0[1][k], xB.x, bias[1][k])));
        }
        cA = sigm(gA[1]) * cA + sigm(gA[0]) * tanh_f(gA[2]);
        cB = sigm(gB[1]) * cB + sigm(gB[0]) * tanh_f(gB[2]);
        float pA = sigm(gA[3]) * tanh_f(cA) * whr[0];
        float pB = sigm(gB[3]) * tanh_f(cB) * whr[1];
        wave_sum2(pA, pB);
        hA = pA; hB = pB;
        if (lane == 0) {
            h1[((size_t)b * TLEN + t) * 2 + 0] = hA;
            h1[((size_t)b * TLEN + (TLEN - 1 - t)) * 2 + 1] = hB;
        }
        xA = xAn; xB = xBn;
    }
}

__global__ __launch_bounds__(256) void mean_kernel(
    const float2* __restrict__ h1, float* __restrict__ out)
{
    int i = blockIdx.x * 256 + threadIdx.x;
    if (i < BATCH * TLEN) {
        float2 v = h1[i];
        out[i] = 0.5f * (v.x + v.y);
    }
}

// ===========================================================================
extern "C" void kernel_launch(void* const* d_in, const int* in_sizes, int n_in,
                              void* d_out, int out_size, void* d_ws, size_t ws_size,
                              hipStream_t stream)
{
    const float* ccba_num = (const float*)d_in[0];
    const int*   ccba_bi  = (const int*)d_in[1];
    const int*   ccba_ti  = (const int*)d_in[2];
    const float* ccba_W   = (const float*)d_in[3];
    const float* ccba_b   = (const float*)d_in[4];
    const float* cdtx_num = (const float*)d_in[5];
    const int*   cdtx_cat = (const int*)d_in[6];
    const float* cdtx_tab = (const float*)d_in[7];
    const int*   cdtx_bi  = (const int*)d_in[8];
    const int*   cdtx_ti  = (const int*)d_in[9];
    const float* cdtx_W   = (const float*)d_in[10];
    const float* cdtx_b   = (const float*)d_in[11];
    const float* cust_num = (const float*)d_in[12];
    const int*   cust_cat = (const int*)d_in[13];
    const float* cust_tab = (const float*)d_in[14];
    const int*   cust_bi  = (const int*)d_in[15];
    const int*   cust_ti  = (const int*)d_in[16];
    const float* cust_W   = (const float*)d_in[17];
    const float* cust_b   = (const float*)d_in[18];
    const float* dp_num   = (const float*)d_in[19];
    const int*   dp_cat   = (const int*)d_in[20];
    const float* dp_tab   = (const float*)d_in[21];
    const int*   dp_bi    = (const int*)d_in[22];
    const int*   dp_ti    = (const int*)d_in[23];
    const float* dp_W     = (const float*)d_in[24];
    const float* dp_b     = (const float*)d_in[25];
    const float* remit_num = (const float*)d_in[26];
    const int*   remit_cat = (const int*)d_in[27];
    const float* remit_tab = (const float*)d_in[28];
    const int*   remit_bi  = (const int*)d_in[29];
    const int*   remit_ti  = (const int*)d_in[30];
    const float* remit_W   = (const float*)d_in[31];
    const float* remit_b   = (const float*)d_in[32];
    const float* Wih0 = (const float*)d_in[33];
    const float* Whh0 = (const float*)d_in[34];
    const float* Whr0 = (const float*)d_in[35];
    const float* bih0 = (const float*)d_in[36];
    const float* bhh0 = (const float*)d_in[37];
    const float* Wih1 = (const float*)d_in[38];
    const float* Whh1 = (const float*)d_in[39];
    const float* Whr1 = (const float*)d_in[40];
    const float* bih1 = (const float*)d_in[41];
    const float* bhh1 = (const float*)d_in[42];

    float* out = (float*)d_out;

    // Workspace:
    //   gf, gb : 1000 * tcm * 256 * 4 each (chunk gates, L3-resident)
    //   h0, h1 : 4,096,000 each | wp 266,240 | hs 8,000 | cs 512,000
    //   order 2,048,000 | cnt 10,240 | startp 10,272 | cur 10,240
    const size_t FIXED = 4096000ull + 4096000ull + 266240ull + 8000ull + 512000ull
                       + 2048000ull + 10240ull + 10272ull + 10240ull;
    size_t avail = (ws_size > FIXED) ? (ws_size - FIXED) : 0;
    int tcm = (int)(avail / 2048000ull);
    if (tcm < 1) tcm = 1;
    if (tcm > 86) tcm = 86;          // gf+gb <= 176 MB -> L3-resident
    if (tcm >= 2) tcm &= ~1;

    char* ws = (char*)d_ws;
    const size_t gfB = (size_t)tcm * 1024000ull;
    float* gf    = (float*)ws;
    float* gb    = (float*)(ws + gfB);
    char*  fixed = ws + 2 * gfB;
    float* h0    = (float*)fixed;
    float* h1    = (float*)(fixed + 4096000ull);
    float* wp    = (float*)(fixed + 8192000ull);
    float* hs    = (float*)(fixed + 8192000ull + 266240ull);
    float* cs    = (float*)(fixed + 8192000ull + 266240ull + 8000ull);
    int*   order = (int*)  (fixed + 8192000ull + 266240ull + 8000ull + 512000ull);
    int*   cnt   = (int*)  (fixed + 8192000ull + 266240ull + 8000ull + 512000ull + 2048000ull);
    int*   startp= (int*)  (fixed + 8192000ull + 266240ull + 8000ull + 512000ull + 2048000ull + 10240ull);
    int*   cur   = (int*)  (fixed + 8192000ull + 266240ull + 8000ull + 512000ull + 2048000ull + 10240ull + 10272ull);

    bin_zero_kernel<<<10, 256, 0, stream>>>(cnt);
    compose_kernel<<<130, 512, 0, stream>>>(
        ccba_W, ccba_b, cdtx_W, cdtx_b, cust_W, cust_b,
        dp_W, dp_b, remit_W, remit_b, Wih0, bih0, bhh0, wp);
    bin_count_kernel<<<dim3(NEVS / 256, 5), 256, 0, stream>>>(
        ccba_ti, cdtx_ti, cust_ti, dp_ti, remit_ti, cnt);
    bin_scan_kernel<<<5, 512, 0, stream>>>(cnt, startp, cur);
    bin_scatter_kernel<<<dim3(NEVS / 256, 5), 256, 0, stream>>>(
        ccba_ti, cdtx_ti, cust_ti, dp_ti, remit_ti, cur, order);

    int first = 1;
    for (int f0 = 0; f0 < TLEN; f0 += tcm) {
        const int len = (TLEN - f0 < tcm) ? (TLEN - f0) : tcm;
        project_tile_kernel<<<dim3(26, 10), 512, 0, stream>>>(
            ccba_num, ccba_bi, ccba_ti,
            cdtx_num, cdtx_cat, cdtx_tab, cdtx_bi, cdtx_ti,
            cust_num, cust_cat, cust_tab, cust_bi, cust_ti,
            dp_num, dp_cat, dp_tab, dp_bi, dp_ti,
            remit_num, remit_cat, remit_tab, remit_bi, remit_ti,
            wp, order, startp, gf, gb, f0, len, tcm);
        rec_chunk_kernel<<<500, 256, 0, stream>>>(
            gf, gb, Whh0, Whr0, h0, hs, cs, f0, len, tcm, first);
        first = 0;
    }

    lstm1_kernel<<<250, 256, 0, stream>>>(h0, Wih1, Whh1, Whr1, bih1, bhh1, h1);
    mean_kernel<<<(BATCH * TLEN + 255) / 256, 256, 0, stream>>>((const float2*)h1, out);
}

// Round 11
// 3992.984 us; speedup vs baseline: 2.4817x; 2.4817x over previous
//
#include <hip/hip_runtime.h>
#include <cstdint>
#include <cstddef>

#define TLEN 512
#define BATCH 1000
#define NEVS 102400   // events per source
#define HID 64

__device__ __forceinline__ float fast_rcp(float x) {
#if __has_builtin(__builtin_amdgcn_rcpf)
    return __builtin_amdgcn_rcpf(x);
#else
    return 1.0f / x;
#endif
}
__device__ __forceinline__ float sigm(float x) { return fast_rcp(1.0f + __expf(-x)); }
__device__ __forceinline__ float tanh_f(float x) { return fmaf(2.0f, sigm(2.0f * x), -1.0f); }

// Wave-wide sum broadcast (rocPRIM gfx9 DPP pattern).
__device__ __forceinline__ float wave_sum_bcast(float x) {
#if __has_builtin(__builtin_amdgcn_update_dpp) && __has_builtin(__builtin_amdgcn_readlane)
    x += __int_as_float(__builtin_amdgcn_update_dpp(0, __float_as_int(x), 0x111, 0xf, 0xf, true)); // row_shr:1
    x += __int_as_float(__builtin_amdgcn_update_dpp(0, __float_as_int(x), 0x112, 0xf, 0xf, true)); // row_shr:2
    x += __int_as_float(__builtin_amdgcn_update_dpp(0, __float_as_int(x), 0x114, 0xf, 0xf, true)); // row_shr:4
    x += __int_as_float(__builtin_amdgcn_update_dpp(0, __float_as_int(x), 0x118, 0xf, 0xf, true)); // row_shr:8
    x += __int_as_float(__builtin_amdgcn_update_dpp(0, __float_as_int(x), 0x142, 0xa, 0xf, true)); // row_bcast:15
    x += __int_as_float(__builtin_amdgcn_update_dpp(0, __float_as_int(x), 0x143, 0xc, 0xf, true)); // row_bcast:31
    return __int_as_float(__builtin_amdgcn_readlane(__float_as_int(x), 63));
#else
#pragma unroll
    for (int off = 1; off < 64; off <<= 1) x += __shfl_xor(x, off, 64);
    return x;
#endif
}

// Two independent wave sums, stages interleaved for ILP.
__device__ __forceinline__ void wave_sum2(float& a, float& b) {
#if __has_builtin(__builtin_amdgcn_update_dpp) && __has_builtin(__builtin_amdgcn_readlane)
    int ta, tb;
    ta = __builtin_amdgcn_update_dpp(0, __float_as_int(a), 0x111, 0xf, 0xf, true);
    tb = __builtin_amdgcn_update_dpp(0, __float_as_int(b), 0x111, 0xf, 0xf, true);
    a += __int_as_float(ta); b += __int_as_float(tb);
    ta = __builtin_amdgcn_update_dpp(0, __float_as_int(a), 0x112, 0xf, 0xf, true);
    tb = __builtin_amdgcn_update_dpp(0, __float_as_int(b), 0x112, 0xf, 0xf, true);
    a += __int_as_float(ta); b += __int_as_float(tb);
    ta = __builtin_amdgcn_update_dpp(0, __float_as_int(a), 0x114, 0xf, 0xf, true);
    tb = __builtin_amdgcn_update_dpp(0, __float_as_int(b), 0x114, 0xf, 0xf, true);
    a += __int_as_float(ta); b += __int_as_float(tb);
    ta = __builtin_amdgcn_update_dpp(0, __float_as_int(a), 0x118, 0xf, 0xf, true);
    tb = __builtin_amdgcn_update_dpp(0, __float_as_int(b), 0x118, 0xf, 0xf, true);
    a += __int_as_float(ta); b += __int_as_float(tb);
    ta = __builtin_amdgcn_update_dpp(0, __float_as_int(a), 0x142, 0xa, 0xf, true);
    tb = __builtin_amdgcn_update_dpp(0, __float_as_int(b), 0x142, 0xa, 0xf, true);
    a += __int_as_float(ta); b += __int_as_float(tb);
    ta = __builtin_amdgcn_update_dpp(0, __float_as_int(a), 0x143, 0xc, 0xf, true);
    tb = __builtin_amdgcn_update_dpp(0, __float_as_int(b), 0x143, 0xc, 0xf, true);
    a += __int_as_float(ta); b += __int_as_float(tb);
    a = __int_as_float(__builtin_amdgcn_readlane(__float_as_int(a), 63));
    b = __int_as_float(__builtin_amdgcn_readlane(__float_as_int(b), 63));
#else
    a = wave_sum_bcast(a); b = wave_sum_bcast(b);
#endif
}

// ===========================================================================
// map[b*512+t] = src<<20 | e  (sources partition the (b,t) grid: exactly one)
// ===========================================================================
__global__ __launch_bounds__(256) void map_build_kernel(
    const int* __restrict__ b0, const int* __restrict__ t0,
    const int* __restrict__ b1, const int* __restrict__ t1,
    const int* __restrict__ b2, const int* __restrict__ t2,
    const int* __restrict__ b3, const int* __restrict__ t3,
    const int* __restrict__ b4, const int* __restrict__ t4,
    int* __restrict__ map)
{
    const int src = blockIdx.y;
    const int* bi = src == 0 ? b0 : src == 1 ? b1 : src == 2 ? b2 : src == 3 ? b3 : b4;
    const int* ti = src == 0 ? t0 : src == 1 ? t1 : src == 2 ? t2 : src == 3 ? t3 : t4;
    const int e = blockIdx.x * 256 + threadIdx.x;
    map[bi[e] * TLEN + ti[e]] = (src << 20) | e;
}

// ===========================================================================
// Binning: per-(src,ti) counts -> prefix starts.
// ===========================================================================
__global__ __launch_bounds__(256) void bin_zero_kernel(int* __restrict__ cnt)
{
    int i = blockIdx.x * 256 + threadIdx.x;
    if (i < 5 * 512) cnt[i] = 0;
}

__global__ __launch_bounds__(256) void bin_count_kernel(
    const int* __restrict__ t0, const int* __restrict__ t1,
    const int* __restrict__ t2, const int* __restrict__ t3,
    const int* __restrict__ t4, int* __restrict__ cnt)
{
    const int src = blockIdx.y;
    const int* ti = src == 0 ? t0 : src == 1 ? t1 : src == 2 ? t2 : src == 3 ? t3 : t4;
    const int e = blockIdx.x * 256 + threadIdx.x;
    atomicAdd(&cnt[src * 512 + ti[e]], 1);
}

__global__ __launch_bounds__(512) void bin_scan_kernel(
    const int* __restrict__ cnt, int* __restrict__ startp)
{
    const int src = blockIdx.x, tid = threadIdx.x;
    __shared__ int s[512];
    const int v = cnt[src * 512 + tid];
    s[tid] = v;
    __syncthreads();
    for (int off = 1; off < 512; off <<= 1) {
        int t = (tid >= off) ? s[tid - off] : 0;
        __syncthreads();
        s[tid] += t;
        __syncthreads();
    }
    const int inc = s[tid];
    startp[src * 513 + tid] = inc - v;
    if (tid == 511) startp[src * 513 + 512] = inc;
}

// ===========================================================================
// order_build: deterministic (ti, bi)-sorted order per source, via map.
// Block = one t value; rank of b within (src,t) = prefix count over b' < b.
// Result: events of one (src, ti-range) are contiguous AND bi-ascending ->
// project's writes to the [lt][b] chunk layout are consecutive rows.
// ===========================================================================
__global__ __launch_bounds__(1024) void order_build_kernel(
    const int* __restrict__ map, const int* __restrict__ startp,
    int* __restrict__ order)
{
    const int t = blockIdx.x, b = threadIdx.x;
    __shared__ int sc[1024];
    int mc = 0, src = -1;
    if (b < BATCH) { mc = map[b * TLEN + t]; src = mc >> 20; }
#pragma unroll 1
    for (int s = 0; s < 5; ++s) {
        int f = (src == s) ? 1 : 0;
        sc[b] = f;
        __syncthreads();
        for (int off = 1; off < 1024; off <<= 1) {
            int v = (b >= off) ? sc[b - off] : 0;
            __syncthreads();
            sc[b] += v;
            __syncthreads();
        }
        if (src == s) {
            const int rank = sc[b] - 1;
            order[(size_t)s * NEVS + startp[s * 513 + t] + rank] = mc & 0xFFFFF;
        }
        __syncthreads();
    }
}

// ===========================================================================
// Composed projection weights: wp[row][col], row=(src,j) [130], col=dir*256+r.
// row j<IND: W_src[j] . Wih0[col]; row j==IND: b_src . Wih0[col] + bih+bhh.
// ===========================================================================
__global__ __launch_bounds__(512) void compose_kernel(
    const float* __restrict__ W0, const float* __restrict__ B0,
    const float* __restrict__ W1, const float* __restrict__ B1,
    const float* __restrict__ W2, const float* __restrict__ B2,
    const float* __restrict__ W3, const float* __restrict__ B3,
    const float* __restrict__ W4, const float* __restrict__ B4,
    const float* __restrict__ Wih, const float* __restrict__ bih,
    const float* __restrict__ bhh, float* __restrict__ wp)
{
    const int col = threadIdx.x;   // 0..511 == dir*256 + r == Wih row index
    const int row = blockIdx.x;    // 0..129
    const float* srcW; const float* srcB; int base, IND;
    if (row < 9)        { srcW = W0; srcB = B0; base = 0;   IND = 8;  }
    else if (row < 27)  { srcW = W1; srcB = B1; base = 9;   IND = 17; }
    else if (row < 53)  { srcW = W2; srcB = B2; base = 27;  IND = 25; }
    else if (row < 120) { srcW = W3; srcB = B3; base = 53;  IND = 66; }
    else                { srcW = W4; srcB = B4; base = 120; IND = 9;  }
    const int j = row - base;
    const float* xrow = (j < IND) ? (srcW + (size_t)j * 64) : srcB;
    const float* wr = Wih + (size_t)col * 64;
    float acc = 0.0f;
#pragma unroll
    for (int h2 = 0; h2 < 64; ++h2) acc = fmaf(xrow[h2], wr[h2], acc);
    if (j == IND) acc += bih[col] + bhh[col];
    wp[(size_t)row * 512 + col] = acc;
}

__device__ __forceinline__ void fma4(float4& a, float x, const float4 w) {
    a.x = fmaf(x, w.x, a.x); a.y = fmaf(x, w.y, a.y);
    a.z = fmaf(x, w.z, a.z); a.w = fmaf(x, w.w, a.w);
}

// ===========================================================================
// Projection v3: wave-autonomous event streams against LDS-resident weights.
// Wave = one event at a time: per-lane gather -> own LDS slot -> broadcast
// dot (x b128 broadcast + w b128 contiguous, conflict-free) -> 1KB store.
// Events are (ti,bi)-sorted -> a wave's consecutive stores hit CONSECUTIVE
// rows of the [lt][b] chunk buffer (r10's scatter amplification killed).
// 1-deep software pipeline hides the gather chain under the dot.
// ===========================================================================
template<int NB, int NR, int SRC>
__device__ __forceinline__ void proj_loop(
    const float* __restrict__ num, const int* __restrict__ cat,
    const float* __restrict__ tab, const int* __restrict__ bi,
    const int* __restrict__ ti,
    const int* __restrict__ order_s, const int* __restrict__ start_s,
    const float* __restrict__ wTs, float (*xb)[2][72],
    float* __restrict__ gdst, int dir, int lo, int hi)
{
    const int lane = threadIdx.x & 63, wv = threadIdx.x >> 6;
    const int r0 = start_s[lo], r1 = start_s[hi];
    const int nw = (int)gridDim.x * 8;
    const int per = (r1 - r0 + nw - 1) / nw;
    const int wg = (int)blockIdx.x * 8 + wv;
    int i0 = r0 + wg * per;
    int i1 = i0 + per; if (i1 > r1) i1 = r1;
    if (i0 >= i1) return;

    auto load_x = [&](int e, float& v0, float& v1) {
        const int v = lane;
        v0 = 0.f; v1 = 0.f;
        if (SRC == 0) {
            if (v < 8) v0 = num[(size_t)e * 8 + v];
            else if (v == 8) v0 = 1.f;
        } else if (SRC == 1) {
            if (v < 16) v0 = tab[(size_t)cat[e * 2 + (v >> 3)] * 8 + (v & 7)];
            else if (v == 16) v0 = num[e];
            else if (v == 17) v0 = 1.f;
        } else if (SRC == 2) {
            if (v < 24) v0 = tab[(size_t)cat[e * 3 + (v >> 3)] * 8 + (v & 7)];
            else if (v == 24) v0 = num[e];
            else if (v == 25) v0 = 1.f;
        } else if (SRC == 3) {
            v0 = tab[(size_t)cat[e * 8 + (v >> 3)] * 8 + (v & 7)];
            if (v < 2) v1 = num[(size_t)e * 2 + v];
            else if (v == 2) v1 = 1.f;
        } else {
            if (v < 8) v0 = tab[(size_t)cat[e] * 8 + v];
            else if (v == 8) v0 = num[e];
            else if (v == 9) v0 = 1.f;
        }
    };

    int e = order_s[i0];
    int posr;
    { const int t = ti[e]; const int lt = dir ? (hi - 1 - t) : (t - lo);
      posr = lt * 1000 + bi[e]; }
    float xv0, xv1;
    load_x(e, xv0, xv1);

#pragma unroll 1
    for (int i = i0; i < i1; ++i) {
        const int buf = i & 1;
        xb[wv][buf][lane] = xv0;
        if (SRC == 3 && lane < 4) xb[wv][buf][64 + lane] = xv1;
        int posn = 0;
        if (i + 1 < i1) {                       // prefetch next event
            const int en = order_s[i + 1];
            const int tn = ti[en];
            const int ltn = dir ? (hi - 1 - tn) : (tn - lo);
            posn = ltn * 1000 + bi[en];
            load_x(en, xv0, xv1);
        }
        float4 acc = make_float4(0.f, 0.f, 0.f, 0.f);
#pragma unroll
        for (int g = 0; g < NB; ++g) {
            const float4 x4 = *(const float4*)&xb[wv][buf][4 * g];  // broadcast
            const float* w = wTs + (size_t)(4 * g) * 256 + 4 * lane;
            fma4(acc, x4.x, *(const float4*)(w));
            fma4(acc, x4.y, *(const float4*)(w + 256));
            fma4(acc, x4.z, *(const float4*)(w + 512));
            fma4(acc, x4.w, *(const float4*)(w + 768));
        }
        *(float4*)&gdst[(size_t)posr * 256 + 4 * lane] = acc;
        posr = posn;
    }
}

__global__ __launch_bounds__(512, 4) void project_kernel(
    const float* __restrict__ ccba_num, const int* __restrict__ ccba_bi, const int* __restrict__ ccba_ti,
    const float* __restrict__ cdtx_num, const int* __restrict__ cdtx_cat, const float* __restrict__ cdtx_tab,
    const int* __restrict__ cdtx_bi, const int* __restrict__ cdtx_ti,
    const float* __restrict__ cust_num, const int* __restrict__ cust_cat, const float* __restrict__ cust_tab,
    const int* __restrict__ cust_bi, const int* __restrict__ cust_ti,
    const float* __restrict__ dp_num, const int* __restrict__ dp_cat, const float* __restrict__ dp_tab,
    const int* __restrict__ dp_bi, const int* __restrict__ dp_ti,
    const float* __restrict__ remit_num, const int* __restrict__ remit_cat, const float* __restrict__ remit_tab,
    const int* __restrict__ remit_bi, const int* __restrict__ remit_ti,
    const float* __restrict__ wp, const int* __restrict__ order, const int* __restrict__ startp,
    float* __restrict__ gf, float* __restrict__ gb,
    int f0, int len)
{
    __shared__ float wTs[68 * 256];     // 69.6 KB: this (src,dir)'s rows only
    __shared__ float xbuf[8][2][72];    // 4.6 KB per-wave double-buffered x

    const int tid = threadIdx.x;
    const int dir = blockIdx.y & 1;
    const int src = blockIdx.y >> 1;
    const int lo = dir ? (TLEN - f0 - len) : f0;   // bwd chunk = mirrored range
    const int hi = lo + len;
    float* gdst = dir ? gb : gf;

    const int NRs[5] = {9, 18, 26, 67, 10};
    const int BAs[5] = {0, 9, 27, 53, 120};
    const int NBs[5] = {3, 5, 7, 17, 3};
    const int nr = NRs[src], ba = BAs[src], nb = NBs[src];
    {
        const float4* wp4 = (const float4*)wp;   // 130 rows x 128 float4
        float4* w4 = (float4*)wTs;
        const int tot = nb * 4 * 64;
        for (int i = tid; i < tot; i += 512) {
            const int row = i >> 6, c4 = i & 63;
            w4[i] = (row < nr) ? wp4[(size_t)(ba + row) * 128 + dir * 64 + c4]
                               : make_float4(0.f, 0.f, 0.f, 0.f);
        }
    }
    __syncthreads();

    const int* order_s = order + (size_t)src * NEVS;
    const int* start_s = startp + src * 513;
    switch (src) {
    case 0: proj_loop<3, 9, 0>(ccba_num, nullptr, nullptr, ccba_bi, ccba_ti,
                               order_s, start_s, wTs, xbuf, gdst, dir, lo, hi); break;
    case 1: proj_loop<5, 18, 1>(cdtx_num, cdtx_cat, cdtx_tab, cdtx_bi, cdtx_ti,
                                order_s, start_s, wTs, xbuf, gdst, dir, lo, hi); break;
    case 2: proj_loop<7, 26, 2>(cust_num, cust_cat, cust_tab, cust_bi, cust_ti,
                                order_s, start_s, wTs, xbuf, gdst, dir, lo, hi); break;
    case 3: proj_loop<17, 67, 3>(dp_num, dp_cat, dp_tab, dp_bi, dp_ti,
                                 order_s, start_s, wTs, xbuf, gdst, dir, lo, hi); break;
    default: proj_loop<3, 10, 4>(remit_num, remit_cat, remit_tab, remit_bi, remit_ti,
                                 order_s, start_s, wTs, xbuf, gdst, dir, lo, hi); break;
    }
}

// ===========================================================================
// Layer-0 recurrence over the chunk (r2-proven structure; [lt][b] layout):
// one wave per (b,dir); 2000 concurrent chains; 2-step gate prefetch.
// ===========================================================================
__global__ __launch_bounds__(256) void rec_chunk_kernel(
    const float* __restrict__ gf, const float* __restrict__ gb,
    const float* __restrict__ Whh, const float* __restrict__ Whr,
    float* __restrict__ h0, float* __restrict__ hs, float* __restrict__ cs,
    int f0, int len, int first)
{
    const int wv = threadIdx.x >> 6, lane = threadIdx.x & 63;
    const int p = blockIdx.x * 4 + wv;          // 0..1999
    const int b = p >> 1, dir = p & 1;

    float whh4[4];
#pragma unroll
    for (int k = 0; k < 4; ++k) whh4[k] = Whh[dir * 256 + k * 64 + lane];
    const float whr = Whr[dir * HID + lane];

    const float* g = (dir ? gb : gf) + (size_t)b * 256 + lane;
    float* h0p = h0 + (size_t)b * TLEN * 2 + dir;

    float h, c;
    if (first) { h = 0.0f; c = 0.0f; }
    else       { h = hs[p]; c = cs[(size_t)p * 64 + lane]; }

    auto ga = [&](int s) -> const float* {
        const int sc = (s < len) ? s : (len - 1);   // clamp; value unused past end
        return g + (size_t)sc * 256000;             // [lt][1000 rows of 256]
    };
    auto do_step = [&](const float (&G)[4], int s) {
        const float gi = fmaf(whh4[0], h, G[0]);
        const float gfv = fmaf(whh4[1], h, G[1]);
        const float gg = fmaf(whh4[2], h, G[2]);
        const float go = fmaf(whh4[3], h, G[3]);
        c = sigm(gfv) * c + sigm(gi) * tanh_f(gg);
        h = wave_sum_bcast(sigm(go) * tanh_f(c) * whr);
        const int t_out = dir ? (TLEN - 1 - f0 - s) : (f0 + s);
        if (lane == 0) h0p[(size_t)t_out * 2] = h;
    };

    float A[4], B[4];
    {
        const float* pa = ga(0); const float* pb = ga(1);
#pragma unroll
        for (int k = 0; k < 4; ++k) { A[k] = pa[k * 64]; B[k] = pb[k * 64]; }
    }
    for (int s = 0; s < len; s += 2) {
        float C[4], D[4];
        const float* pc = ga(s + 2); const float* pd = ga(s + 3);
#pragma unroll
        for (int k = 0; k < 4; ++k) { C[k] = pc[k * 64]; D[k] = pd[k * 64]; }
        do_step(A, s);
        if (s + 1 < len) do_step(B, s + 1);
#pragma unroll
        for (int k = 0; k < 4; ++k) { A[k] = C[k]; B[k] = D[k]; }
    }
    if (lane == 0) hs[p] = h;
    cs[(size_t)p * 64 + lane] = c;
}

// ===========================================================================
// LSTM layer 1 (insz=2): one wave per b, BOTH dirs interleaved; x staged
// in LDS (serial chain is x-load-latency-bound at 178 us otherwise).
// ===========================================================================
__global__ __launch_bounds__(256, 2) void lstm1_kernel(
    const float* __restrict__ h0, const float* __restrict__ Wih,
    const float* __restrict__ Whh, const float* __restrict__ Whr,
    const float* __restrict__ bih, const float* __restrict__ bhh,
    float* __restrict__ h1)
{
    __shared__ float2 xsh[4][TLEN];
    const int w = threadIdx.x >> 6, lane = threadIdx.x & 63;
    const int b0 = blockIdx.x * 4;
    const int b = b0 + w;                      // grid 250 -> b 0..999

    {
        const float2* src = (const float2*)(h0 + (size_t)b0 * TLEN * 2);
        for (int i = threadIdx.x; i < 4 * TLEN; i += 256)
            xsh[i >> 9][i & 511] = src[i];
    }

    const volatile float* vWih = Wih;
    const volatile float* vWhh = Whh;
    const volatile float* vWhr = Whr;
    const volatile float* vbih = bih;
    const volatile float* vbhh = bhh;

    float wi0[2][4], wi1[2][4], whh[2][4], bias[2][4], whr[2];
#pragma unroll
    for (int d = 0; d < 2; ++d) {
#pragma unroll
        for (int k = 0; k < 4; ++k) {
            const int r = d * 256 + k * 64 + lane;
            wi0[d][k] = vWih[(size_t)r * 2 + 0];
            wi1[d][k] = vWih[(size_t)r * 2 + 1];
            whh[d][k] = vWhh[r];
            bias[d][k] = vbih[r] + vbhh[r];
        }
        whr[d] = vWhr[d * HID + lane];
    }
    __syncthreads();

    float hA = 0, cA = 0, hB = 0, cB = 0;
    const float2* hb = xsh[w];

    float2 xA = hb[0];            // fwd t=0
    float2 xB = hb[TLEN - 1];     // bwd t=511
    for (int t = 0; t < TLEN; ++t) {
        const int tn = (t + 1 < TLEN) ? t + 1 : t;
        const float2 xAn = hb[tn];
        const float2 xBn = hb[TLEN - 1 - tn];
        float gA[4], gB[4];
#pragma unroll
        for (int k = 0; k < 4; ++k) {
            gA[k] = fmaf(whh[0][k], hA, fmaf(wi1[0][k], xA.y, fmaf(wi0[0][k], xA.x, bias[0][k])));
            gB[k] = fmaf(whh[1][k], hB, fmaf(wi1[1][k], xB.y, fmaf(wi0[1][k], xB.x, bias[1][k])));
        }
        cA = sigm(gA[1]) * cA + sigm(gA[0]) * tanh_f(gA[2]);
        cB = sigm(gB[1]) * cB + sigm(gB[0]) * tanh_f(gB[2]);
        float pA = sigm(gA[3]) * tanh_f(cA) * whr[0];
        float pB = sigm(gB[3]) * tanh_f(cB) * whr[1];
        wave_sum2(pA, pB);
        hA = pA; hB = pB;
        if (lane == 0) {
            h1[((size_t)b * TLEN + t) * 2 + 0] = hA;
            h1[((size_t)b * TLEN + (TLEN - 1 - t)) * 2 + 1] = hB;
        }
        xA = xAn; xB = xBn;
    }
}

__global__ __launch_bounds__(256) void mean_kernel(
    const float2* __restrict__ h1, float* __restrict__ out)
{
    int i = blockIdx.x * 256 + threadIdx.x;
    if (i < BATCH * TLEN) {
        float2 v = h1[i];
        out[i] = 0.5f * (v.x + v.y);
    }
}

// ===========================================================================
extern "C" void kernel_launch(void* const* d_in, const int* in_sizes, int n_in,
                              void* d_out, int out_size, void* d_ws, size_t ws_size,
                              hipStream_t stream)
{
    const float* ccba_num = (const float*)d_in[0];
    const int*   ccba_bi  = (const int*)d_in[1];
    const int*   ccba_ti  = (const int*)d_in[2];
    const float* ccba_W   = (const float*)d_in[3];
    const float* ccba_b   = (const float*)d_in[4];
    const float* cdtx_num = (const float*)d_in[5];
    const int*   cdtx_cat = (const int*)d_in[6];
    const float* cdtx_tab = (const float*)d_in[7];
    const int*   cdtx_bi  = (const int*)d_in[8];
    const int*   cdtx_ti  = (const int*)d_in[9];
    const float* cdtx_W   = (const float*)d_in[10];
    const float* cdtx_b   = (const float*)d_in[11];
    const float* cust_num = (const float*)d_in[12];
    const int*   cust_cat = (const int*)d_in[13];
    const float* cust_tab = (const float*)d_in[14];
    const int*   cust_bi  = (const int*)d_in[15];
    const int*   cust_ti  = (const int*)d_in[16];
    const float* cust_W   = (const float*)d_in[17];
    const float* cust_b   = (const float*)d_in[18];
    const float* dp_num   = (const float*)d_in[19];
    const int*   dp_cat   = (const int*)d_in[20];
    const float* dp_tab   = (const float*)d_in[21];
    const int*   dp_bi    = (const int*)d_in[22];
    const int*   dp_ti    = (const int*)d_in[23];
    const float* dp_W     = (const float*)d_in[24];
    const float* dp_b     = (const float*)d_in[25];
    const float* remit_num = (const float*)d_in[26];
    const int*   remit_cat = (const int*)d_in[27];
    const float* remit_tab = (const float*)d_in[28];
    const int*   remit_bi  = (const int*)d_in[29];
    const int*   remit_ti  = (const int*)d_in[30];
    const float* remit_W   = (const float*)d_in[31];
    const float* remit_b   = (const float*)d_in[32];
    const float* Wih0 = (const float*)d_in[33];
    const float* Whh0 = (const float*)d_in[34];
    const float* Whr0 = (const float*)d_in[35];
    const float* bih0 = (const float*)d_in[36];
    const float* bhh0 = (const float*)d_in[37];
    const float* Wih1 = (const float*)d_in[38];
    const float* Whh1 = (const float*)d_in[39];
    const float* Whr1 = (const float*)d_in[40];
    const float* bih1 = (const float*)d_in[41];
    const float* bhh1 = (const float*)d_in[42];

    float* out = (float*)d_out;

    // Workspace: gf, gb (tcm * 1.024 MB each, [lt][b] layout) then fixed:
    //   h0 4,096,000 | h1 4,096,000 | wp 266,240 | hs 8,000 | cs 512,000
    //   map 2,048,000 | order 2,048,000 | cnt 10,240 | startp 10,272
    const size_t FIXED = 4096000ull + 4096000ull + 266240ull + 8000ull + 512000ull
                       + 2048000ull + 2048000ull + 10240ull + 10272ull;
    size_t avail = (ws_size > FIXED) ? (ws_size - FIXED) : 0;
    int tcm = (int)(avail / 2048000ull);
    if (tcm < 1) tcm = 1;
    if (tcm > 86) tcm = 86;          // gf+gb <= 176 MB -> L3-resident
    if (tcm >= 2) tcm &= ~1;

    char* ws = (char*)d_ws;
    const size_t gfB = (size_t)tcm * 1024000ull;
    float* gf    = (float*)ws;
    float* gb    = (float*)(ws + gfB);
    char*  fixed = ws + 2 * gfB;
    float* h0    = (float*)fixed;
    float* h1    = (float*)(fixed + 4096000ull);
    float* wp    = (float*)(fixed + 8192000ull);
    float* hs    = (float*)(fixed + 8192000ull + 266240ull);
    float* cs    = (float*)(fixed + 8192000ull + 266240ull + 8000ull);
    int*   map   = (int*)  (fixed + 8192000ull + 266240ull + 8000ull + 512000ull);
    int*   order = (int*)  (fixed + 8192000ull + 266240ull + 8000ull + 512000ull + 2048000ull);
    int*   cnt   = (int*)  (fixed + 8192000ull + 266240ull + 8000ull + 512000ull + 4096000ull);
    int*   startp= (int*)  (fixed + 8192000ull + 266240ull + 8000ull + 512000ull + 4096000ull + 10240ull);

    bin_zero_kernel<<<10, 256, 0, stream>>>(cnt);
    compose_kernel<<<130, 512, 0, stream>>>(
        ccba_W, ccba_b, cdtx_W, cdtx_b, cust_W, cust_b,
        dp_W, dp_b, remit_W, remit_b, Wih0, bih0, bhh0, wp);
    map_build_kernel<<<dim3(NEVS / 256, 5), 256, 0, stream>>>(
        ccba_bi, ccba_ti, cdtx_bi, cdtx_ti, cust_bi, cust_ti,
        dp_bi, dp_ti, remit_bi, remit_ti, map);
    bin_count_kernel<<<dim3(NEVS / 256, 5), 256, 0, stream>>>(
        ccba_ti, cdtx_ti, cust_ti, dp_ti, remit_ti, cnt);
    bin_scan_kernel<<<5, 512, 0, stream>>>(cnt, startp);
    order_build_kernel<<<TLEN, 1024, 0, stream>>>(map, startp, order);

    int first = 1;
    for (int f0 = 0; f0 < TLEN; f0 += tcm) {
        const int len = (TLEN - f0 < tcm) ? (TLEN - f0) : tcm;
        project_kernel<<<dim3(52, 10), 512, 0, stream>>>(
            ccba_num, ccba_bi, ccba_ti,
            cdtx_num, cdtx_cat, cdtx_tab, cdtx_bi, cdtx_ti,
            cust_num, cust_cat, cust_tab, cust_bi, cust_ti,
            dp_num, dp_cat, dp_tab, dp_bi, dp_ti,
            remit_num, remit_cat, remit_tab, remit_bi, remit_ti,
            wp, order, startp, gf, gb, f0, len);
        rec_chunk_kernel<<<500, 256, 0, stream>>>(
            gf, gb, Whh0, Whr0, h0, hs, cs, f0, len, first);
        first = 0;
    }

    lstm1_kernel<<<250, 256, 0, stream>>>(h0, Wih1, Whh1, Whr1, bih1, bhh1, h1);
    mean_kernel<<<(BATCH * TLEN + 255) / 256, 256, 0, stream>>>((const float2*)h1, out);
}

// Round 12
// 1425.857 us; speedup vs baseline: 6.9497x; 2.8004x over previous
//
#include <hip/hip_runtime.h>
#include <cstdint>
#include <cstddef>

#define TLEN 512
#define BATCH 1000
#define NEVS 102400   // events per source
#define HID 64
#define W0S 8         // fused0 steps per phase
#define NP (TLEN / W0S)

__device__ __forceinline__ float fast_rcp(float x) {
#if __has_builtin(__builtin_amdgcn_rcpf)
    return __builtin_amdgcn_rcpf(x);
#else
    return 1.0f / x;
#endif
}
__device__ __forceinline__ float sigm(float x) { return fast_rcp(1.0f + __expf(-x)); }
__device__ __forceinline__ float tanh_f(float x) { return fmaf(2.0f, sigm(2.0f * x), -1.0f); }

// Wave-wide sum broadcast (rocPRIM gfx9 DPP pattern).
__device__ __forceinline__ float wave_sum_bcast(float x) {
#if __has_builtin(__builtin_amdgcn_update_dpp) && __has_builtin(__builtin_amdgcn_readlane)
    x += __int_as_float(__builtin_amdgcn_update_dpp(0, __float_as_int(x), 0x111, 0xf, 0xf, true)); // row_shr:1
    x += __int_as_float(__builtin_amdgcn_update_dpp(0, __float_as_int(x), 0x112, 0xf, 0xf, true)); // row_shr:2
    x += __int_as_float(__builtin_amdgcn_update_dpp(0, __float_as_int(x), 0x114, 0xf, 0xf, true)); // row_shr:4
    x += __int_as_float(__builtin_amdgcn_update_dpp(0, __float_as_int(x), 0x118, 0xf, 0xf, true)); // row_shr:8
    x += __int_as_float(__builtin_amdgcn_update_dpp(0, __float_as_int(x), 0x142, 0xa, 0xf, true)); // row_bcast:15
    x += __int_as_float(__builtin_amdgcn_update_dpp(0, __float_as_int(x), 0x143, 0xc, 0xf, true)); // row_bcast:31
    return __int_as_float(__builtin_amdgcn_readlane(__float_as_int(x), 63));
#else
#pragma unroll
    for (int off = 1; off < 64; off <<= 1) x += __shfl_xor(x, off, 64);
    return x;
#endif
}

// Two independent wave sums, stages interleaved for ILP.
__device__ __forceinline__ void wave_sum2(float& a, float& b) {
#if __has_builtin(__builtin_amdgcn_update_dpp) && __has_builtin(__builtin_amdgcn_readlane)
    int ta, tb;
    ta = __builtin_amdgcn_update_dpp(0, __float_as_int(a), 0x111, 0xf, 0xf, true);
    tb = __builtin_amdgcn_update_dpp(0, __float_as_int(b), 0x111, 0xf, 0xf, true);
    a += __int_as_float(ta); b += __int_as_float(tb);
    ta = __builtin_amdgcn_update_dpp(0, __float_as_int(a), 0x112, 0xf, 0xf, true);
    tb = __builtin_amdgcn_update_dpp(0, __float_as_int(b), 0x112, 0xf, 0xf, true);
    a += __int_as_float(ta); b += __int_as_float(tb);
    ta = __builtin_amdgcn_update_dpp(0, __float_as_int(a), 0x114, 0xf, 0xf, true);
    tb = __builtin_amdgcn_update_dpp(0, __float_as_int(b), 0x114, 0xf, 0xf, true);
    a += __int_as_float(ta); b += __int_as_float(tb);
    ta = __builtin_amdgcn_update_dpp(0, __float_as_int(a), 0x118, 0xf, 0xf, true);
    tb = __builtin_amdgcn_update_dpp(0, __float_as_int(b), 0x118, 0xf, 0xf, true);
    a += __int_as_float(ta); b += __int_as_float(tb);
    ta = __builtin_amdgcn_update_dpp(0, __float_as_int(a), 0x142, 0xa, 0xf, true);
    tb = __builtin_amdgcn_update_dpp(0, __float_as_int(b), 0x142, 0xa, 0xf, true);
    a += __int_as_float(ta); b += __int_as_float(tb);
    ta = __builtin_amdgcn_update_dpp(0, __float_as_int(a), 0x143, 0xc, 0xf, true);
    tb = __builtin_amdgcn_update_dpp(0, __float_as_int(b), 0x143, 0xc, 0xf, true);
    a += __int_as_float(ta); b += __int_as_float(tb);
    a = __int_as_float(__builtin_amdgcn_readlane(__float_as_int(a), 63));
    b = __int_as_float(__builtin_amdgcn_readlane(__float_as_int(b), 63));
#else
    a = wave_sum_bcast(a); b = wave_sum_bcast(b);
#endif
}

// ===========================================================================
// map[b*512+t] = src<<20 | e  (sources partition the (b,t) grid: exactly one)
// ===========================================================================
__global__ __launch_bounds__(256) void map_build_kernel(
    const int* __restrict__ b0, const int* __restrict__ t0,
    const int* __restrict__ b1, const int* __restrict__ t1,
    const int* __restrict__ b2, const int* __restrict__ t2,
    const int* __restrict__ b3, const int* __restrict__ t3,
    const int* __restrict__ b4, const int* __restrict__ t4,
    int* __restrict__ map)
{
    const int src = blockIdx.y;
    const int* bi = src == 0 ? b0 : src == 1 ? b1 : src == 2 ? b2 : src == 3 ? b3 : b4;
    const int* ti = src == 0 ? t0 : src == 1 ? t1 : src == 2 ? t2 : src == 3 ? t3 : t4;
    const int e = blockIdx.x * 256 + threadIdx.x;
    map[bi[e] * TLEN + ti[e]] = (src << 20) | e;
}

// ===========================================================================
// Composed projection weights: wp[row][col], row=(src,j) [130], col=dir*256+r.
// row j<IND: W_src[j] . Wih0[col]; row j==IND: b_src . Wih0[col] + bih+bhh.
// ===========================================================================
__global__ __launch_bounds__(512) void compose_kernel(
    const float* __restrict__ W0, const float* __restrict__ B0,
    const float* __restrict__ W1, const float* __restrict__ B1,
    const float* __restrict__ W2, const float* __restrict__ B2,
    const float* __restrict__ W3, const float* __restrict__ B3,
    const float* __restrict__ W4, const float* __restrict__ B4,
    const float* __restrict__ Wih, const float* __restrict__ bih,
    const float* __restrict__ bhh, float* __restrict__ wp)
{
    const int col = threadIdx.x;   // 0..511 == dir*256 + r == Wih row index
    const int row = blockIdx.x;    // 0..129
    const float* srcW; const float* srcB; int base, IND;
    if (row < 9)        { srcW = W0; srcB = B0; base = 0;   IND = 8;  }
    else if (row < 27)  { srcW = W1; srcB = B1; base = 9;   IND = 17; }
    else if (row < 53)  { srcW = W2; srcB = B2; base = 27;  IND = 25; }
    else if (row < 120) { srcW = W3; srcB = B3; base = 53;  IND = 66; }
    else                { srcW = W4; srcB = B4; base = 120; IND = 9;  }
    const int j = row - base;
    const float* xrow = (j < IND) ? (srcW + (size_t)j * 64) : srcB;
    const float* wr = Wih + (size_t)col * 64;
    float acc = 0.0f;
#pragma unroll
    for (int h2 = 0; h2 < 64; ++h2) acc = fmaf(xrow[h2], wr[h2], acc);
    if (j == IND) acc += bih[col] + bhh[col];
    wp[(size_t)row * 512 + col] = acc;
}

// ===========================================================================
// dot4: event x over a source's padded row range against LDS weights.
// Wave = one event -> w reads are full-row contiguous b128 (conflict-free),
// x reads are uniform (broadcast). 16 FMA per 5 LDS ops.
// ===========================================================================
template<int NB, int BASE>
__device__ __forceinline__ float4 dot4(const float* wT, const float* xb, int colq) {
    float ax = 0.f, ay = 0.f, az = 0.f, aw = 0.f;
#pragma unroll
    for (int jb = 0; jb < NB; ++jb) {
        const float4 x4 = *(const float4*)(xb + 4 * jb);
        const float* w = wT + (size_t)(BASE + 4 * jb) * 256 + 4 * colq;
        const float4 w0 = *(const float4*)(w);
        const float4 w1 = *(const float4*)(w + 256);
        const float4 w2 = *(const float4*)(w + 512);
        const float4 w3 = *(const float4*)(w + 768);
        ax = fmaf(x4.x, w0.x, ax); ay = fmaf(x4.x, w0.y, ay);
        az = fmaf(x4.x, w0.z, az); aw = fmaf(x4.x, w0.w, aw);
        ax = fmaf(x4.y, w1.x, ax); ay = fmaf(x4.y, w1.y, ay);
        az = fmaf(x4.y, w1.z, az); aw = fmaf(x4.y, w1.w, aw);
        ax = fmaf(x4.z, w2.x, ax); ay = fmaf(x4.z, w2.y, ay);
        az = fmaf(x4.z, w2.z, az); aw = fmaf(x4.z, w2.w, aw);
        ax = fmaf(x4.w, w3.x, ax); ay = fmaf(x4.w, w3.y, ay);
        az = fmaf(x4.w, w3.z, az); aw = fmaf(x4.w, w3.w, aw);
    }
    return make_float4(ax, ay, az, aw);
}

// ===========================================================================
// Fused layer-0 (r7-measured, 1160 us): weights in LDS. Block = (b,dir),
// 576 threads: 8 producer waves (wave = event) + 1 consumer wave.
// 3-stage pipeline: gather(p+2) || A1(p+1) || recurrence B(p).
// LDS: wT 135.2K + winP 8K*2 + xbuf 2.2K*2 + mcls = ~156 KB (1 block/CU).
// ===========================================================================
__global__ __launch_bounds__(576, 1) void fused0_kernel(
    const float* __restrict__ ccba_num,
    const float* __restrict__ cdtx_num, const int* __restrict__ cdtx_cat, const float* __restrict__ cdtx_tab,
    const float* __restrict__ cust_num, const int* __restrict__ cust_cat, const float* __restrict__ cust_tab,
    const float* __restrict__ dp_num,   const int* __restrict__ dp_cat,   const float* __restrict__ dp_tab,
    const float* __restrict__ remit_num, const int* __restrict__ remit_cat, const float* __restrict__ remit_tab,
    const float* __restrict__ wp, const int* __restrict__ map,
    const float* __restrict__ Whh, const float* __restrict__ Whr,
    float* __restrict__ h0)
{
    __shared__ float wT[132 * 256];          // [row][col], rows 130/131 zeroed
    __shared__ float winP[2][W0S][256];
    __shared__ float xbuf[2][W0S][68];       // padded x (bias=1.0 folded in)
    __shared__ int   mcls[2][W0S];

    const int tid = threadIdx.x;
    const int b = blockIdx.x >> 1, dir = blockIdx.x & 1;

    // ---- stage weights: this dir's 256-col half of every row ----
    {
        const float4* wp4 = (const float4*)wp;   // 130 rows x 128 float4
        float4* wT4 = (float4*)wT;
        for (int i = tid; i < 130 * 64; i += 576) {
            const int row = i >> 6, c4 = i & 63;
            wT4[(row << 6) + c4] = wp4[(row << 7) + (dir << 6) + c4];
        }
        if (tid < 128) wT4[130 * 64 + tid] = make_float4(0.f, 0.f, 0.f, 0.f);
    }

    // ---- consumer state (wave 8) ----
    float whh4[4] = {0.f, 0.f, 0.f, 0.f};
    float whr = 0.f, h = 0.f, c = 0.f;
    float* h0p = h0 + (size_t)b * TLEN * 2 + dir;
    if (tid >= 512) {
        const int lane = tid - 512;
#pragma unroll
        for (int k = 0; k < 4; ++k) whh4[k] = Whh[dir * 256 + k * 64 + lane];
        whr = Whr[dir * HID + lane];
    }

    struct GR { float v0, v1; int mc; };

    // gather: wave = one event, lane v loads one padded-x value.
    auto g_load = [&](int P) -> GR {
        GR g; g.v0 = 0.f; g.v1 = 0.f;
        const int ev = tid >> 6, v = tid & 63;
        const int s = P * W0S + ev;
        const int t = dir ? (TLEN - 1 - s) : s;
        g.mc = map[b * TLEN + t];
        const int src = g.mc >> 20, e = g.mc & 0xFFFFF;
        switch (src) {
        case 0:
            g.v0 = (v < 8) ? ccba_num[(size_t)e * 8 + v] : (v == 8 ? 1.0f : 0.0f);
            break;
        case 1:
            g.v0 = (v < 16) ? cdtx_tab[(size_t)cdtx_cat[e * 2 + (v >> 3)] * 8 + (v & 7)]
                 : (v == 16 ? cdtx_num[e] : (v == 17 ? 1.0f : 0.0f));
            break;
        case 2:
            g.v0 = (v < 24) ? cust_tab[(size_t)cust_cat[e * 3 + (v >> 3)] * 8 + (v & 7)]
                 : (v == 24 ? cust_num[e] : (v == 25 ? 1.0f : 0.0f));
            break;
        case 3:
            g.v0 = dp_tab[(size_t)dp_cat[e * 8 + (v >> 3)] * 8 + (v & 7)];
            if (v < 4) g.v1 = (v < 2) ? dp_num[(size_t)e * 2 + v] : (v == 2 ? 1.0f : 0.0f);
            break;
        default:
            g.v0 = (v < 8) ? remit_tab[(size_t)remit_cat[e] * 8 + v]
                 : (v == 8 ? remit_num[e] : (v == 9 ? 1.0f : 0.0f));
            break;
        }
        return g;
    };
    auto g_store = [&](const GR& g, int P) {
        const int buf = P & 1;
        const int ev = tid >> 6, v = tid & 63;
        if (v == 0) mcls[buf][ev] = g.mc;
        const int src = g.mc >> 20;
        const int pad = (src == 0) ? 12 : (src == 1) ? 20 : (src == 2) ? 28
                      : (src == 3) ? 64 : 12;
        if (v < pad) xbuf[buf][ev][v] = g.v0;
        if (src == 3 && v < 4) xbuf[buf][ev][64 + v] = g.v1;
    };

    // A1: thread = (event, col-quad); wave-uniform source branch.
    auto a1 = [&](int P) {
        const int buf = P & 1;
        const int ev = tid >> 6, colq = tid & 63;
        const int src = mcls[buf][ev] >> 20;
        const float* xb = xbuf[buf][ev];
        float4 acc;
        switch (src) {
        case 0:  acc = dot4<3, 0>(wT, xb, colq);   break;
        case 1:  acc = dot4<5, 9>(wT, xb, colq);   break;
        case 2:  acc = dot4<7, 27>(wT, xb, colq);  break;
        case 3:  acc = dot4<17, 53>(wT, xb, colq); break;
        default: acc = dot4<3, 120>(wT, xb, colq); break;
        }
        ((float4*)winP[buf][ev])[colq] = acc;
    };

    // B: consumer wave runs W0S recurrence steps for phase P.
    auto bstep = [&](int P) {
        const int buf = P & 1;
        const int lane = tid - 512;
        for (int sl = 0; sl < W0S; ++sl) {
            const float gi = fmaf(whh4[0], h, winP[buf][sl][lane]);
            const float gf = fmaf(whh4[1], h, winP[buf][sl][64 + lane]);
            const float gg = fmaf(whh4[2], h, winP[buf][sl][128 + lane]);
            const float go = fmaf(whh4[3], h, winP[buf][sl][192 + lane]);
            c = sigm(gf) * c + sigm(gi) * tanh_f(gg);
            h = wave_sum_bcast(sigm(go) * tanh_f(c) * whr);
            const int s = P * W0S + sl;
            const int tt = dir ? (TLEN - 1 - s) : s;
            if (lane == 0) h0p[(size_t)tt * 2] = h;
        }
    };

    // ---- prologue ----
    if (tid < 512) { GR g0 = g_load(0); g_store(g0, 0); }
    __syncthreads();                      // wT + xbuf[0] ready
    if (tid < 512) { GR g1 = g_load(1); a1(0); g_store(g1, 1); }
    __syncthreads();                      // winP[0] + xbuf[1] ready

    // ---- main loop: gather(p+2) || A1(p+1) || B(p) ----
    for (int p = 0; p < NP; ++p) {
        if (tid < 512) {
            GR g{};
            const bool hg = (p + 2 < NP);
            if (hg) g = g_load(p + 2);
            if (p + 1 < NP) a1(p + 1);
            if (hg) g_store(g, p + 2);
        } else if (tid < 576) {
            bstep(p);
        }
        __syncthreads();
    }
}

// ===========================================================================
// LSTM layer 1 (insz=2): one wave per b, BOTH dirs as two interleaved chains;
// x staged in LDS (r2 1-chain and r7 2-chain both measured exactly 178 us ->
// the serial chain is x-LOAD-latency-bound; LDS reads put it back to
// issue-bound). Volatile weight loads keep weights resident.
// ===========================================================================
__global__ __launch_bounds__(256, 2) void lstm1_kernel(
    const float* __restrict__ h0, const float* __restrict__ Wih,
    const float* __restrict__ Whh, const float* __restrict__ Whr,
    const float* __restrict__ bih, const float* __restrict__ bhh,
    float* __restrict__ h1)
{
    __shared__ float2 xsh[4][TLEN];
    const int w = threadIdx.x >> 6, lane = threadIdx.x & 63;
    const int b0 = blockIdx.x * 4;
    const int b = b0 + w;                      // grid 250 -> b 0..999

    {
        const float2* src = (const float2*)(h0 + (size_t)b0 * TLEN * 2);
        for (int i = threadIdx.x; i < 4 * TLEN; i += 256)
            xsh[i >> 9][i & 511] = src[i];
    }

    const volatile float* vWih = Wih;
    const volatile float* vWhh = Whh;
    const volatile float* vWhr = Whr;
    const volatile float* vbih = bih;
    const volatile float* vbhh = bhh;

    float wi0[2][4], wi1[2][4], whh[2][4], bias[2][4], whr[2];
#pragma unroll
    for (int d = 0; d < 2; ++d) {
#pragma unroll
        for (int k = 0; k < 4; ++k) {
            const int r = d * 256 + k * 64 + lane;
            wi0[d][k] = vWih[(size_t)r * 2 + 0];
            wi1[d][k] = vWih[(size_t)r * 2 + 1];
            whh[d][k] = vWhh[r];
            bias[d][k] = vbih[r] + vbhh[r];
        }
        whr[d] = vWhr[d * HID + lane];
    }
    __syncthreads();

    float hA = 0, cA = 0, hB = 0, cB = 0;
    const float2* hb = xsh[w];

    float2 xA = hb[0];            // fwd t=0
    float2 xB = hb[TLEN - 1];     // bwd t=511
    for (int t = 0; t < TLEN; ++t) {
        const int tn = (t + 1 < TLEN) ? t + 1 : t;
        const float2 xAn = hb[tn];
        const float2 xBn = hb[TLEN - 1 - tn];
        float gA[4], gB[4];
#pragma unroll
        for (int k = 0; k < 4; ++k) {
            gA[k] = fmaf(whh[0][k], hA, fmaf(wi1[0][k], xA.y, fmaf(wi0[0][k], xA.x, bias[0][k])));
            gB[k] = fmaf(whh[1][k], hB, fmaf(wi1[1][k], xB.y, fmaf(wi0[1][k], xB.x, bias[1][k])));
        }
        cA = sigm(gA[1]) * cA + sigm(gA[0]) * tanh_f(gA[2]);
        cB = sigm(gB[1]) * cB + sigm(gB[0]) * tanh_f(gB[2]);
        float pA = sigm(gA[3]) * tanh_f(cA) * whr[0];
        float pB = sigm(gB[3]) * tanh_f(cB) * whr[1];
        wave_sum2(pA, pB);
        hA = pA; hB = pB;
        if (lane == 0) {
            h1[((size_t)b * TLEN + t) * 2 + 0] = hA;
            h1[((size_t)b * TLEN + (TLEN - 1 - t)) * 2 + 1] = hB;
        }
        xA = xAn; xB = xBn;
    }
}

__global__ __launch_bounds__(256) void mean_kernel(
    const float2* __restrict__ h1, float* __restrict__ out)
{
    int i = blockIdx.x * 256 + threadIdx.x;
    if (i < BATCH * TLEN) {
        float2 v = h1[i];
        out[i] = 0.5f * (v.x + v.y);
    }
}

// ===========================================================================
extern "C" void kernel_launch(void* const* d_in, const int* in_sizes, int n_in,
                              void* d_out, int out_size, void* d_ws, size_t ws_size,
                              hipStream_t stream)
{
    const float* ccba_num = (const float*)d_in[0];
    const int*   ccba_bi  = (const int*)d_in[1];
    const int*   ccba_ti  = (const int*)d_in[2];
    const float* ccba_W   = (const float*)d_in[3];
    const float* ccba_b   = (const float*)d_in[4];
    const float* cdtx_num = (const float*)d_in[5];
    const int*   cdtx_cat = (const int*)d_in[6];
    const float* cdtx_tab = (const float*)d_in[7];
    const int*   cdtx_bi  = (const int*)d_in[8];
    const int*   cdtx_ti  = (const int*)d_in[9];
    const float* cdtx_W   = (const float*)d_in[10];
    const float* cdtx_b   = (const float*)d_in[11];
    const float* cust_num = (const float*)d_in[12];
    const int*   cust_cat = (const int*)d_in[13];
    const float* cust_tab = (const float*)d_in[14];
    const int*   cust_bi  = (const int*)d_in[15];
    const int*   cust_ti  = (const int*)d_in[16];
    const float* cust_W   = (const float*)d_in[17];
    const float* cust_b   = (const float*)d_in[18];
    const float* dp_num   = (const float*)d_in[19];
    const int*   dp_cat   = (const int*)d_in[20];
    const float* dp_tab   = (const float*)d_in[21];
    const int*   dp_bi    = (const int*)d_in[22];
    const int*   dp_ti    = (const int*)d_in[23];
    const float* dp_W     = (const float*)d_in[24];
    const float* dp_b     = (const float*)d_in[25];
    const float* remit_num = (const float*)d_in[26];
    const int*   remit_cat = (const int*)d_in[27];
    const float* remit_tab = (const float*)d_in[28];
    const int*   remit_bi  = (const int*)d_in[29];
    const int*   remit_ti  = (const int*)d_in[30];
    const float* remit_W   = (const float*)d_in[31];
    const float* remit_b   = (const float*)d_in[32];
    const float* Wih0 = (const float*)d_in[33];
    const float* Whh0 = (const float*)d_in[34];
    const float* Whr0 = (const float*)d_in[35];
    const float* bih0 = (const float*)d_in[36];
    const float* bhh0 = (const float*)d_in[37];
    const float* Wih1 = (const float*)d_in[38];
    const float* Whh1 = (const float*)d_in[39];
    const float* Whr1 = (const float*)d_in[40];
    const float* bih1 = (const float*)d_in[41];
    const float* bhh1 = (const float*)d_in[42];

    float* out = (float*)d_out;

    // Workspace: wp (266,240) | map (2,048,000) | h0 (4,096,000) | h1 (4,096,000)
    char* ws = (char*)d_ws;
    float* wp  = (float*)ws;
    int*   map = (int*)  (ws + 266240ull);
    float* h0  = (float*)(ws + 266240ull + 2048000ull);
    float* h1  = (float*)(ws + 266240ull + 2048000ull + 4096000ull);

    compose_kernel<<<130, 512, 0, stream>>>(
        ccba_W, ccba_b, cdtx_W, cdtx_b, cust_W, cust_b,
        dp_W, dp_b, remit_W, remit_b, Wih0, bih0, bhh0, wp);

    map_build_kernel<<<dim3(NEVS / 256, 5), 256, 0, stream>>>(
        ccba_bi, ccba_ti, cdtx_bi, cdtx_ti, cust_bi, cust_ti,
        dp_bi, dp_ti, remit_bi, remit_ti, map);

    fused0_kernel<<<2 * BATCH, 576, 0, stream>>>(
        ccba_num,
        cdtx_num, cdtx_cat, cdtx_tab,
        cust_num, cust_cat, cust_tab,
        dp_num, dp_cat, dp_tab,
        remit_num, remit_cat, remit_tab,
        wp, map, Whh0, Whr0, h0);

    lstm1_kernel<<<250, 256, 0, stream>>>(h0, Wih1, Whh1, Whr1, bih1, bhh1, h1);
    mean_kernel<<<(BATCH * TLEN + 255) / 256, 256, 0, stream>>>((const float2*)h1, out);
}